// Round 11
// baseline (204.874 us; speedup 1.0000x reference)
//
#include <hip/hip_runtime.h>

#define NPTS 32768
#define NBLKS 256
#define TPB 512          // 8 waves/block, 16 points/wave -> 128 points/block
#define MAXSTEPS 24
#define N3 (NPTS*3)

typedef __attribute__((ext_vector_type(8))) short short8;
typedef __attribute__((ext_vector_type(4))) float f32x4;
union U8 { uint4 v; short8 s; };

__device__ __forceinline__ float fast_tanh(float x) {
    float e = __expf(2.0f * x);
    return fmaf(-2.0f, __builtin_amdgcn_rcpf(1.0f + e), 1.0f);
}
__device__ __forceinline__ uint32_t bf16_rne(float x) {      // init path only
    uint32_t u = __float_as_uint(x);
    return (u + 0x7FFFu + ((u >> 16) & 1u)) >> 16;
}
__device__ __forceinline__ uint32_t hi16f(float x) { return __float_as_uint(x) >> 16; }
__device__ __forceinline__ uint32_t lo16f(float x) {
    uint32_t hu = __float_as_uint(x) & 0xFFFF0000u;
    return bf16_rne(x - __uint_as_float(hu));
}
// hot-path split: hi = truncation, lo = round-half-up of residual
__device__ __forceinline__ void split_pair(float x0, float x1, uint32_t& hw, uint32_t& lw) {
    uint32_t u0 = __float_as_uint(x0), u1 = __float_as_uint(x1);
    float l0 = x0 - __uint_as_float(u0 & 0xFFFF0000u);
    float l1 = x1 - __uint_as_float(u1 & 0xFFFF0000u);
    hw = (u0 >> 16) | (u1 & 0xFFFF0000u);
    uint32_t a0 = __float_as_uint(l0) + 0x8000u;
    uint32_t a1 = __float_as_uint(l1) + 0x8000u;
    lw = (a0 >> 16) | (a1 & 0xFFFF0000u);
}
__device__ __forceinline__ unsigned long long ld_slot(const unsigned long long* p) {
    return __hip_atomic_load(p, __ATOMIC_RELAXED, __HIP_MEMORY_SCOPE_AGENT);
}

// launch_bounds(TPB, 1): min 1 wave/EU -> compiler register budget 512/wave
// (256 arch + 256 agpr). Grid is structurally 1 block/CU (256 blocks), so HW
// occupancy (2 waves/SIMD) is unchanged for any arch use <= 256. The previous
// (TPB,2) budgeted 128 arch regs -> persistent scratch spill (r8-r10: 230-433MB
// FETCH). This is the only change vs r10.
__global__ void __launch_bounds__(TPB, 1)
ode_persist(const float* __restrict__ yin,
            const float* __restrict__ W1, const float* __restrict__ b1,
            const float* __restrict__ W2, const float* __restrict__ b2,
            const float* __restrict__ W3, const float* __restrict__ b3,
            float* __restrict__ out,
            unsigned long long* __restrict__ slots)
{
    // per-quad broadcast tables. Strides (68/52/20 dwords) put the 4 per-wave
    // base addresses on disjoint bank quartets; 16-lane groups share addresses
    // (broadcast). All reads b128, conflict-free.
    __shared__ float w1tab[4*68];   // [q][i=0..15][4: x,y,z,t]
    __shared__ float w3tab[4*52];   // [q][a][j=0..11], j=3r+d
    __shared__ float b2tab[4*20];   // [q][a][r]
    __shared__ float cs8[8];
    __shared__ float vbox;

    const int tid  = threadIdx.x;
    const int lane = tid & 63;
    const int l15  = lane & 15;
    const int q    = (lane >> 4) & 3;
    const int w    = __builtin_amdgcn_readfirstlane(tid >> 6);
    const int gp   = (int)blockIdx.x * 128 + 16*w + l15;

    // ---- init tables (once): exactly one element per thread ----
    if (tid < 256) {
        const int tq = tid >> 6, ti = (tid >> 2) & 15, tc = tid & 3;
        const int n  = 32*(ti >> 3) + 8*tq + (ti & 7);
        w1tab[tq*68 + ti*4 + tc] = W1[tc*64 + n];
    } else if (tid < 448) {
        const int u = tid - 256;
        const int tq = u / 48, rem = u % 48, a = rem / 12, j = rem % 12;
        w3tab[tq*52 + a*12 + j] = W3[(16*a + 4*tq + j/3)*3 + (j % 3)];
    } else {
        const int u = tid - 448;
        const int tq = u >> 4, i = u & 15;
        b2tab[tq*20 + i] = b2[16*(i >> 2) + 4*tq + (i & 3)];
    }

    // ---- per-lane params (once) ----
    float w1b[16];                       // biases for this lane's 16 neurons
    #pragma unroll
    for (int i = 0; i < 16; ++i)
        w1b[i] = b1[32*(i >> 3) + 8*q + (i & 7)];

    short8 w2h[4][2], w2l[4][2];         // MFMA A operands -> AGPR-eligible
    #pragma unroll
    for (int a = 0; a < 4; ++a) {
        const int n = 16*a + l15;
        #pragma unroll
        for (int h = 0; h < 2; ++h) {
            uint32_t dh[4], dl[4];
            #pragma unroll
            for (int j2 = 0; j2 < 4; ++j2) {
                const int k0 = 32*h + 8*q + 2*j2;
                const float w0 = W2[k0*64 + n], w1v = W2[(k0+1)*64 + n];
                dh[j2] = hi16f(w0) | (hi16f(w1v) << 16);
                dl[j2] = lo16f(w0) | (lo16f(w1v) << 16);
            }
            U8 uh; uh.v = make_uint4(dh[0], dh[1], dh[2], dh[3]); w2h[a][h] = uh.s;
            U8 ul; ul.v = make_uint4(dl[0], dl[1], dl[2], dl[3]); w2l[a][h] = ul.s;
        }
    }
    const float b30 = b3[0], b31 = b3[1], b32s = b3[2];

    __syncthreads();                     // tables ready

    float y0 = yin[3*gp], y1 = yin[3*gp+1], y2 = yin[3*gp+2];
    float t = 0.f, dt = 0.05f;
    float ks[7][3];
    const f32x4* wrow  = (const f32x4*)&w1tab[q*68];   // 17 f32x4 stride
    const f32x4* w3row = (const f32x4*)&w3tab[q*52];   // 13 f32x4 stride
    const f32x4* b2row = (const f32x4*)&b2tab[q*20];   // 5  f32x4 stride

    auto feval = [&](float ts, float yi0, float yi1, float yi2, float* kout) {
        // ---- layer 1: fp32 VALU, weights from static LDS broadcast table ----
        uint32_t bh[8], bl[8];
        #pragma unroll
        for (int i2 = 0; i2 < 8; ++i2) {
            const int i0 = 2*i2, i1 = i0 + 1;
            const f32x4 wa = wrow[i0], wb = wrow[i1];
            float p0 = fmaf(ts, wa[3], fmaf(yi2, wa[2],
                       fmaf(yi1, wa[1], fmaf(yi0, wa[0], w1b[i0]))));
            float p1 = fmaf(ts, wb[3], fmaf(yi2, wb[2],
                       fmaf(yi1, wb[1], fmaf(yi0, wb[0], w1b[i1]))));
            split_pair(fast_tanh(p0), fast_tanh(p1), bh[i2], bl[i2]);
        }
        U8 bh0, bh1, bl0, bl1;
        bh0.v = make_uint4(bh[0], bh[1], bh[2], bh[3]);
        bh1.v = make_uint4(bh[4], bh[5], bh[6], bh[7]);
        bl0.v = make_uint4(bl[0], bl[1], bl[2], bl[3]);
        bl1.v = make_uint4(bl[4], bl[5], bl[6], bl[7]);

        // ---- layer 2: 24 MFMAs, two 3-deep chains per a-block; fused layer 3 ----
        const f32x4 zero4 = (f32x4)(0.0f);
        float po0 = 0.f, po1 = 0.f, po2 = 0.f;
        #pragma unroll
        for (int a = 0; a < 4; ++a) {
            f32x4 accA = zero4, accB = zero4;
            accA = __builtin_amdgcn_mfma_f32_16x16x32_bf16(w2h[a][0], bh0.s, accA, 0, 0, 0);
            accB = __builtin_amdgcn_mfma_f32_16x16x32_bf16(w2h[a][1], bh1.s, accB, 0, 0, 0);
            accA = __builtin_amdgcn_mfma_f32_16x16x32_bf16(w2h[a][0], bl0.s, accA, 0, 0, 0);
            accB = __builtin_amdgcn_mfma_f32_16x16x32_bf16(w2h[a][1], bl1.s, accB, 0, 0, 0);
            accA = __builtin_amdgcn_mfma_f32_16x16x32_bf16(w2l[a][0], bh0.s, accA, 0, 0, 0);
            accB = __builtin_amdgcn_mfma_f32_16x16x32_bf16(w2l[a][1], bh1.s, accB, 0, 0, 0);
            const f32x4 b2q  = b2row[a];
            const f32x4 w3c0 = w3row[3*a+0], w3c1 = w3row[3*a+1], w3c2 = w3row[3*a+2];
            {   const float h2 = fast_tanh((accA[0] + accB[0]) + b2q[0]);
                po0 = fmaf(h2, w3c0[0], po0); po1 = fmaf(h2, w3c0[1], po1); po2 = fmaf(h2, w3c0[2], po2); }
            {   const float h2 = fast_tanh((accA[1] + accB[1]) + b2q[1]);
                po0 = fmaf(h2, w3c0[3], po0); po1 = fmaf(h2, w3c1[0], po1); po2 = fmaf(h2, w3c1[1], po2); }
            {   const float h2 = fast_tanh((accA[2] + accB[2]) + b2q[2]);
                po0 = fmaf(h2, w3c1[2], po0); po1 = fmaf(h2, w3c1[3], po1); po2 = fmaf(h2, w3c2[0], po2); }
            {   const float h2 = fast_tanh((accA[3] + accB[3]) + b2q[3]);
                po0 = fmaf(h2, w3c2[1], po0); po1 = fmaf(h2, w3c2[2], po1); po2 = fmaf(h2, w3c2[3], po2); }
        }
        po0 += __shfl_xor(po0, 16); po0 += __shfl_xor(po0, 32);
        po1 += __shfl_xor(po1, 16); po1 += __shfl_xor(po1, 32);
        po2 += __shfl_xor(po2, 16); po2 += __shfl_xor(po2, 32);
        kout[0] = po0 + b30; kout[1] = po1 + b31; kout[2] = po2 + b32s;
    };

    // FSAL seed: ks[0] = f(t0, y0) once; reused bit-exactly thereafter
    feval(t, y0, y1, y2, ks[0]);

    for (int s = 0; s < MAXSTEPS; ++s) {
        const float dt_c = fminf(dt, 1.0f - t);

        {   const float a = dt_c * (float)(1.0/5.0);
            feval(fmaf((float)(1.0/5.0), dt_c, t),
                  fmaf(a, ks[0][0], y0), fmaf(a, ks[0][1], y1), fmaf(a, ks[0][2], y2), ks[1]); }
        {   const float a0 = dt_c*(float)(3.0/40.0), a1 = dt_c*(float)(9.0/40.0);
            float yi0 = fmaf(a1, ks[1][0], fmaf(a0, ks[0][0], y0));
            float yi1 = fmaf(a1, ks[1][1], fmaf(a0, ks[0][1], y1));
            float yi2 = fmaf(a1, ks[1][2], fmaf(a0, ks[0][2], y2));
            feval(fmaf((float)(3.0/10.0), dt_c, t), yi0, yi1, yi2, ks[2]); }
        {   const float a0 = dt_c*(float)(44.0/45.0), a1 = dt_c*(float)(-56.0/15.0),
                        a2 = dt_c*(float)(32.0/9.0);
            float yi0 = fmaf(a2, ks[2][0], fmaf(a1, ks[1][0], fmaf(a0, ks[0][0], y0)));
            float yi1 = fmaf(a2, ks[2][1], fmaf(a1, ks[1][1], fmaf(a0, ks[0][1], y1)));
            float yi2 = fmaf(a2, ks[2][2], fmaf(a1, ks[1][2], fmaf(a0, ks[0][2], y2)));
            feval(fmaf((float)(4.0/5.0), dt_c, t), yi0, yi1, yi2, ks[3]); }
        {   const float a0 = dt_c*(float)(19372.0/6561.0), a1 = dt_c*(float)(-25360.0/2187.0),
                        a2 = dt_c*(float)(64448.0/6561.0), a3 = dt_c*(float)(-212.0/729.0);
            float yi0 = fmaf(a3, ks[3][0], fmaf(a2, ks[2][0], fmaf(a1, ks[1][0], fmaf(a0, ks[0][0], y0))));
            float yi1 = fmaf(a3, ks[3][1], fmaf(a2, ks[2][1], fmaf(a1, ks[1][1], fmaf(a0, ks[0][1], y1))));
            float yi2 = fmaf(a3, ks[3][2], fmaf(a2, ks[2][2], fmaf(a1, ks[1][2], fmaf(a0, ks[0][2], y2))));
            feval(fmaf((float)(8.0/9.0), dt_c, t), yi0, yi1, yi2, ks[4]); }
        {   const float a0 = dt_c*(float)(9017.0/3168.0), a1 = dt_c*(float)(-355.0/33.0),
                        a2 = dt_c*(float)(46732.0/5247.0), a3 = dt_c*(float)(49.0/176.0),
                        a4 = dt_c*(float)(-5103.0/18656.0);
            float yi0 = fmaf(a4, ks[4][0], fmaf(a3, ks[3][0], fmaf(a2, ks[2][0], fmaf(a1, ks[1][0], fmaf(a0, ks[0][0], y0)))));
            float yi1 = fmaf(a4, ks[4][1], fmaf(a3, ks[3][1], fmaf(a2, ks[2][1], fmaf(a1, ks[1][1], fmaf(a0, ks[0][1], y1)))));
            float yi2 = fmaf(a4, ks[4][2], fmaf(a3, ks[3][2], fmaf(a2, ks[2][2], fmaf(a1, ks[1][2], fmaf(a0, ks[0][2], y2)))));
            feval(t + dt_c, yi0, yi1, yi2, ks[5]); }
        const float db0 = dt_c*(float)(35.0/384.0), db2 = dt_c*(float)(500.0/1113.0),
                    db3 = dt_c*(float)(125.0/192.0), db4 = dt_c*(float)(-2187.0/6784.0),
                    db5 = dt_c*(float)(11.0/84.0);
        float y5_0 = fmaf(db5, ks[5][0], fmaf(db4, ks[4][0], fmaf(db3, ks[3][0], fmaf(db2, ks[2][0], fmaf(db0, ks[0][0], y0)))));
        float y5_1 = fmaf(db5, ks[5][1], fmaf(db4, ks[4][1], fmaf(db3, ks[3][1], fmaf(db2, ks[2][1], fmaf(db0, ks[0][1], y1)))));
        float y5_2 = fmaf(db5, ks[5][2], fmaf(db4, ks[4][2], fmaf(db3, ks[3][2], fmaf(db2, ks[2][2], fmaf(db0, ks[0][2], y2)))));
        // stage 7 input == y5 bit-exactly (A[6] == B), time t+dt_c  (FSAL)
        feval(t + dt_c, y5_0, y5_1, y5_2, ks[6]);

        const float de0 = dt_c*(float)(35.0/384.0   - 5179.0/57600.0);
        const float de2 = dt_c*(float)(500.0/1113.0 - 7571.0/16695.0);
        const float de3 = dt_c*(float)(125.0/192.0  - 393.0/640.0);
        const float de4 = dt_c*(float)(-2187.0/6784.0 + 92097.0/339200.0);
        const float de5 = dt_c*(float)(11.0/84.0    - 187.0/2100.0);
        const float de6 = dt_c*(float)(-1.0/40.0);
        float e_0 = fmaf(de6, ks[6][0], fmaf(de5, ks[5][0], fmaf(de4, ks[4][0], fmaf(de3, ks[3][0], fmaf(de2, ks[2][0], de0*ks[0][0])))));
        float e_1 = fmaf(de6, ks[6][1], fmaf(de5, ks[5][1], fmaf(de4, ks[4][1], fmaf(de3, ks[3][1], fmaf(de2, ks[2][1], de0*ks[0][1])))));
        float e_2 = fmaf(de6, ks[6][2], fmaf(de5, ks[5][2], fmaf(de4, ks[4][2], fmaf(de3, ks[3][2], fmaf(de2, ks[2][2], de0*ks[0][2])))));

        float e2 = 0.f;
        {   float tol = fmaf(1e-5f, fmaxf(fabsf(y0), fabsf(y5_0)), 1e-5f);
            float r = e_0 * __builtin_amdgcn_rcpf(tol); e2 = fmaf(r,r,e2); }
        {   float tol = fmaf(1e-5f, fmaxf(fabsf(y1), fabsf(y5_1)), 1e-5f);
            float r = e_1 * __builtin_amdgcn_rcpf(tol); e2 = fmaf(r,r,e2); }
        {   float tol = fmaf(1e-5f, fmaxf(fabsf(y2), fabsf(y5_2)), 1e-5f);
            float r = e_2 * __builtin_amdgcn_rcpf(tol); e2 = fmaf(r,r,e2); }

        float es = e2;
        es += __shfl_xor(es, 1); es += __shfl_xor(es, 2);
        es += __shfl_xor(es, 4); es += __shfl_xor(es, 8);
        if (lane == 0) cs8[w] = es;
        __syncthreads();

        unsigned long long* ph = slots + (s & 1)*NBLKS;
        if (w == 0) {
            if (lane == 0) {
                const float bs = ((cs8[0]+cs8[1]) + (cs8[2]+cs8[3]))
                               + ((cs8[4]+cs8[5]) + (cs8[6]+cs8[7]));
                const unsigned long long pack =
                    ((unsigned long long)(unsigned)(s + 1) << 32) |
                    (unsigned long long)__float_as_uint(bs);
                __hip_atomic_store(&ph[blockIdx.x], pack,
                                   __ATOMIC_RELAXED, __HIP_MEMORY_SCOPE_AGENT);
            }
            const unsigned long long m = (unsigned long long)(s + 1);
            unsigned long long u0, u1, u2, u3;
            for (;;) {
                u0 = ld_slot(&ph[lane      ]);
                u1 = ld_slot(&ph[lane +  64]);
                u2 = ld_slot(&ph[lane + 128]);
                u3 = ld_slot(&ph[lane + 192]);
                const bool ok = ((u0 >> 32) == m) & ((u1 >> 32) == m) &
                                ((u2 >> 32) == m) & ((u3 >> 32) == m);
                if (__ballot(ok) == ~0ull) break;
                __builtin_amdgcn_s_sleep(1);
            }
            float v = (__uint_as_float((uint32_t)u0) + __uint_as_float((uint32_t)u1))
                    + (__uint_as_float((uint32_t)u2) + __uint_as_float((uint32_t)u3));
            v += __shfl_xor(v, 1);  v += __shfl_xor(v, 2);  v += __shfl_xor(v, 4);
            v += __shfl_xor(v, 8);  v += __shfl_xor(v, 16); v += __shfl_xor(v, 32);
            if (lane == 0) vbox = v;
        }
        __syncthreads();
        const float v = vbox;

        float err = sqrtf(v / (float)N3);
        err = fmaxf(err, 1e-10f);
        const bool accept = (err <= 1.0f);
        const float factor = fminf(fmaxf(0.9f * __powf(err, -0.2f), 0.2f), 10.0f);
        if (accept) {
            t = t + dt_c; y0 = y5_0; y1 = y5_1; y2 = y5_2;
            ks[0][0] = ks[6][0]; ks[0][1] = ks[6][1]; ks[0][2] = ks[6][2];  // FSAL
        }
        dt = dt_c * factor;
        if ((1.0f - t) <= 1e-9f) break;     // uniform everywhere
    }

    if (q == 0) {
        out[3*gp+0] = y0; out[3*gp+1] = y1; out[3*gp+2] = y2;
    }
}

extern "C" void kernel_launch(void* const* d_in, const int* in_sizes, int n_in,
                              void* d_out, int out_size, void* d_ws, size_t ws_size,
                              hipStream_t stream) {
    const float* y  = (const float*)d_in[0];
    const float* W1 = (const float*)d_in[1];
    const float* b1 = (const float*)d_in[2];
    const float* W2 = (const float*)d_in[3];
    const float* b2 = (const float*)d_in[4];
    const float* W3 = (const float*)d_in[5];
    const float* b3 = (const float*)d_in[6];
    float* out = (float*)d_out;
    // 2 phases x 256 u64 slots; 0xAA poison top-32 never matches markers 1..24.
    unsigned long long* slots = (unsigned long long*)d_ws;

    ode_persist<<<dim3(NBLKS), dim3(TPB), 0, stream>>>(
        y, W1, b1, W2, b2, W3, b3, out, slots);
}

// Round 12
// 135.733 us; speedup vs baseline: 1.5094x; 1.5094x over previous
//
#include <hip/hip_runtime.h>

#define NPTS 32768
#define NBLKS 256
#define TPB 512          // 8 waves/block, 16 points/wave -> 128 points/block
#define MAXSTEPS 24
#define N3 (NPTS*3)

typedef __attribute__((ext_vector_type(8))) short short8;
typedef __attribute__((ext_vector_type(4))) float f32x4;
union U8 { uint4 v; short8 s; };

__device__ __forceinline__ float fast_tanh(float x) {
    float e = __expf(2.0f * x);
    return fmaf(-2.0f, __builtin_amdgcn_rcpf(1.0f + e), 1.0f);
}
__device__ __forceinline__ uint32_t bf16_rne(float x) {      // init path only
    uint32_t u = __float_as_uint(x);
    return (u + 0x7FFFu + ((u >> 16) & 1u)) >> 16;
}
__device__ __forceinline__ uint32_t hi16f(float x) { return __float_as_uint(x) >> 16; }
__device__ __forceinline__ uint32_t lo16f(float x) {
    uint32_t hu = __float_as_uint(x) & 0xFFFF0000u;
    return bf16_rne(x - __uint_as_float(hu));
}
// hot-path split: hi = truncation, lo = round-half-up of residual
__device__ __forceinline__ void split_pair(float x0, float x1, uint32_t& hw, uint32_t& lw) {
    uint32_t u0 = __float_as_uint(x0), u1 = __float_as_uint(x1);
    float l0 = x0 - __uint_as_float(u0 & 0xFFFF0000u);
    float l1 = x1 - __uint_as_float(u1 & 0xFFFF0000u);
    hw = (u0 >> 16) | (u1 & 0xFFFF0000u);
    uint32_t a0 = __float_as_uint(l0) + 0x8000u;
    uint32_t a1 = __float_as_uint(l1) + 0x8000u;
    lw = (a0 >> 16) | (a1 & 0xFFFF0000u);
}
__device__ __forceinline__ uint32_t splo(float x) {          // scalar lo, half-up
    uint32_t hu = __float_as_uint(x) & 0xFFFF0000u;
    return (__float_as_uint(x - __uint_as_float(hu)) + 0x8000u) >> 16;
}
__device__ __forceinline__ unsigned long long ld_slot(const unsigned long long* p) {
    return __hip_atomic_load(p, __ATOMIC_RELAXED, __HIP_MEMORY_SCOPE_AGENT);
}

// r7 structure (validated, spill-free): layer-1 via MFMA (pw1 frags AGPR-
// eligible), H1 hi/lo through XOR-swizzled LDS, FSAL, sleep-barrier.
// Only delta vs r7: layer-2 accumulator chain split 6-deep -> 2x3-deep.
// NOTE (r8-r11 lesson): 512-thread blocks force 2 waves/SIMD -> 256 unified
// regs/wave. Keeping fat arrays as MFMA operands (AGPR) is what makes it fit.
__global__ void __launch_bounds__(TPB, 2)
ode_persist(const float* __restrict__ yin,
            const float* __restrict__ W1, const float* __restrict__ b1,
            const float* __restrict__ W2, const float* __restrict__ b2,
            const float* __restrict__ W3, const float* __restrict__ b3,
            float* __restrict__ out,
            unsigned long long* __restrict__ slots)
{
    __shared__ uint32_t H1hi[8*512];   // per-wave 16 rows x 32 dwords, XOR-swizzled
    __shared__ uint32_t H1lo[8*512];
    __shared__ float    cs8[8];
    __shared__ float    vbox;

    const int tid  = threadIdx.x;
    const int lane = tid & 63;
    const int l15  = lane & 15;
    const int q    = (lane >> 4) & 3;
    const int w    = __builtin_amdgcn_readfirstlane(tid >> 6);
    const int wbase = w * 512;
    const int swz  = (l15 & 7) << 2;
    const int gp   = (int)blockIdx.x * 128 + 16*w + l15;

    // ---- pre-split params in registers (once) ----
    short8 pw1[4], w2h[4][2], w2l[4][2];
    float b2v[4][4], w3f[4][12];
    #pragma unroll
    for (int a = 0; a < 4; ++a) {
        const int n = 16*a + l15;
        uint32_t sl[8];
        #pragma unroll
        for (int j = 0; j < 8; ++j) {
            const int k = 8*q + j;
            uint32_t v = 0;
            if (k < 12) {
                const int i = k / 3, r = k - 3*i;
                const float wv = W1[i*64 + n];
                v = (r == 2) ? lo16f(wv) : hi16f(wv);
            } else if (k == 12) v = hi16f(b1[n]);
            else if (k == 13)   v = lo16f(b1[n]);
            sl[j] = v;
        }
        U8 u; u.v = make_uint4(sl[0]|(sl[1]<<16), sl[2]|(sl[3]<<16),
                               sl[4]|(sl[5]<<16), sl[6]|(sl[7]<<16));
        pw1[a] = u.s;
    }
    #pragma unroll
    for (int a = 0; a < 4; ++a) {
        const int n = 16*a + l15;
        #pragma unroll
        for (int h = 0; h < 2; ++h) {
            uint32_t dh[4], dl[4];
            #pragma unroll
            for (int j2 = 0; j2 < 4; ++j2) {
                const int k0 = 32*h + 8*q + 2*j2;
                const float w0 = W2[k0*64 + n], w1v = W2[(k0+1)*64 + n];
                dh[j2] = hi16f(w0) | (hi16f(w1v) << 16);
                dl[j2] = lo16f(w0) | (lo16f(w1v) << 16);
            }
            U8 uh; uh.v = make_uint4(dh[0], dh[1], dh[2], dh[3]); w2h[a][h] = uh.s;
            U8 ul; ul.v = make_uint4(dl[0], dl[1], dl[2], dl[3]); w2l[a][h] = ul.s;
        }
        #pragma unroll
        for (int r = 0; r < 4; ++r) {
            const int nn = 16*a + 4*q + r;
            b2v[a][r] = b2[nn];
            w3f[a][3*r+0] = W3[nn*3+0];
            w3f[a][3*r+1] = W3[nn*3+1];
            w3f[a][3*r+2] = W3[nn*3+2];
        }
    }
    const float b30 = b3[0], b31 = b3[1], b32s = b3[2];

    float y0 = yin[3*gp], y1 = yin[3*gp+1], y2 = yin[3*gp+2];
    float t = 0.f, dt = 0.05f;
    float ks[7][3];

    auto feval = [&](float ts, float yi0, float yi1, float yi2, float* kout) {
        const uint32_t y0h = hi16f(yi0), y0l = splo(yi0);
        const uint32_t y1h = hi16f(yi1), y1l = splo(yi1);
        const uint32_t y2h = hi16f(yi2), y2l = splo(yi2);
        const uint32_t th_ = hi16f(ts),  tl_ = splo(ts);
        uint32_t bd0, bd1, bd2, bd3;
        if (q == 0)      { bd0 = y0h|(y0l<<16); bd1 = y0h|(y1h<<16);
                           bd2 = y1l|(y1h<<16); bd3 = y2h|(y2l<<16); }
        else if (q == 1) { bd0 = y2h|(th_<<16); bd1 = tl_|(th_<<16);
                           bd2 = 0x3F803F80u;   bd3 = 0u; }
        else             { bd0 = bd1 = bd2 = bd3 = 0u; }
        U8 B1; B1.v = make_uint4(bd0, bd1, bd2, bd3);

        const f32x4 zero4 = (f32x4)(0.0f);
        float h1v[16];
        #pragma unroll
        for (int a = 0; a < 4; ++a) {
            f32x4 c = __builtin_amdgcn_mfma_f32_16x16x32_bf16(pw1[a], B1.s, zero4, 0, 0, 0);
            h1v[4*a+0] = fast_tanh(c[0]); h1v[4*a+1] = fast_tanh(c[1]);
            h1v[4*a+2] = fast_tanh(c[2]); h1v[4*a+3] = fast_tanh(c[3]);
        }
        #pragma unroll
        for (int a = 0; a < 4; ++a) {
            uint32_t hA, lA, hB, lB;
            split_pair(h1v[4*a+0], h1v[4*a+1], hA, lA);
            split_pair(h1v[4*a+2], h1v[4*a+3], hB, lB);
            const int col = wbase + l15*32 + ((8*a + 2*q) ^ swz);
            *(uint2*)&H1hi[col] = make_uint2(hA, hB);
            *(uint2*)&H1lo[col] = make_uint2(lA, lB);
        }
        const int r0 = wbase + l15*32 + ((4*q) ^ swz);
        const int r1 = wbase + l15*32 + ((16 + 4*q) ^ swz);
        U8 bh0, bh1, bl0, bl1;
        bh0.v = *(const uint4*)&H1hi[r0];  bh1.v = *(const uint4*)&H1hi[r1];
        bl0.v = *(const uint4*)&H1lo[r0];  bl1.v = *(const uint4*)&H1lo[r1];

        // layer 2: 24 MFMAs in two 3-deep chains per a-block (r10's split)
        float po0 = 0.f, po1 = 0.f, po2 = 0.f;
        #pragma unroll
        for (int a = 0; a < 4; ++a) {
            f32x4 accA = zero4, accB = zero4;
            accA = __builtin_amdgcn_mfma_f32_16x16x32_bf16(w2h[a][0], bh0.s, accA, 0, 0, 0);
            accB = __builtin_amdgcn_mfma_f32_16x16x32_bf16(w2h[a][1], bh1.s, accB, 0, 0, 0);
            accA = __builtin_amdgcn_mfma_f32_16x16x32_bf16(w2h[a][0], bl0.s, accA, 0, 0, 0);
            accB = __builtin_amdgcn_mfma_f32_16x16x32_bf16(w2h[a][1], bl1.s, accB, 0, 0, 0);
            accA = __builtin_amdgcn_mfma_f32_16x16x32_bf16(w2l[a][0], bh0.s, accA, 0, 0, 0);
            accB = __builtin_amdgcn_mfma_f32_16x16x32_bf16(w2l[a][1], bh1.s, accB, 0, 0, 0);
            #pragma unroll
            for (int r = 0; r < 4; ++r) {
                const float h2 = fast_tanh((accA[r] + accB[r]) + b2v[a][r]);
                po0 = fmaf(h2, w3f[a][3*r+0], po0);
                po1 = fmaf(h2, w3f[a][3*r+1], po1);
                po2 = fmaf(h2, w3f[a][3*r+2], po2);
            }
        }
        po0 += __shfl_xor(po0, 16); po0 += __shfl_xor(po0, 32);
        po1 += __shfl_xor(po1, 16); po1 += __shfl_xor(po1, 32);
        po2 += __shfl_xor(po2, 16); po2 += __shfl_xor(po2, 32);
        kout[0] = po0 + b30; kout[1] = po1 + b31; kout[2] = po2 + b32s;
    };

    // FSAL seed: ks[0] = f(t0, y0) computed ONCE; thereafter reused bit-exactly
    feval(t, y0, y1, y2, ks[0]);

    for (int s = 0; s < MAXSTEPS; ++s) {
        const float dt_c = fminf(dt, 1.0f - t);

        {   const float a = dt_c * (float)(1.0/5.0);
            feval(fmaf((float)(1.0/5.0), dt_c, t),
                  fmaf(a, ks[0][0], y0), fmaf(a, ks[0][1], y1), fmaf(a, ks[0][2], y2), ks[1]); }
        {   const float a0 = dt_c*(float)(3.0/40.0), a1 = dt_c*(float)(9.0/40.0);
            float yi0 = fmaf(a1, ks[1][0], fmaf(a0, ks[0][0], y0));
            float yi1 = fmaf(a1, ks[1][1], fmaf(a0, ks[0][1], y1));
            float yi2 = fmaf(a1, ks[1][2], fmaf(a0, ks[0][2], y2));
            feval(fmaf((float)(3.0/10.0), dt_c, t), yi0, yi1, yi2, ks[2]); }
        {   const float a0 = dt_c*(float)(44.0/45.0), a1 = dt_c*(float)(-56.0/15.0),
                        a2 = dt_c*(float)(32.0/9.0);
            float yi0 = fmaf(a2, ks[2][0], fmaf(a1, ks[1][0], fmaf(a0, ks[0][0], y0)));
            float yi1 = fmaf(a2, ks[2][1], fmaf(a1, ks[1][1], fmaf(a0, ks[0][1], y1)));
            float yi2 = fmaf(a2, ks[2][2], fmaf(a1, ks[1][2], fmaf(a0, ks[0][2], y2)));
            feval(fmaf((float)(4.0/5.0), dt_c, t), yi0, yi1, yi2, ks[3]); }
        {   const float a0 = dt_c*(float)(19372.0/6561.0), a1 = dt_c*(float)(-25360.0/2187.0),
                        a2 = dt_c*(float)(64448.0/6561.0), a3 = dt_c*(float)(-212.0/729.0);
            float yi0 = fmaf(a3, ks[3][0], fmaf(a2, ks[2][0], fmaf(a1, ks[1][0], fmaf(a0, ks[0][0], y0))));
            float yi1 = fmaf(a3, ks[3][1], fmaf(a2, ks[2][1], fmaf(a1, ks[1][1], fmaf(a0, ks[0][1], y1))));
            float yi2 = fmaf(a3, ks[3][2], fmaf(a2, ks[2][2], fmaf(a1, ks[1][2], fmaf(a0, ks[0][2], y2))));
            feval(fmaf((float)(8.0/9.0), dt_c, t), yi0, yi1, yi2, ks[4]); }
        {   const float a0 = dt_c*(float)(9017.0/3168.0), a1 = dt_c*(float)(-355.0/33.0),
                        a2 = dt_c*(float)(46732.0/5247.0), a3 = dt_c*(float)(49.0/176.0),
                        a4 = dt_c*(float)(-5103.0/18656.0);
            float yi0 = fmaf(a4, ks[4][0], fmaf(a3, ks[3][0], fmaf(a2, ks[2][0], fmaf(a1, ks[1][0], fmaf(a0, ks[0][0], y0)))));
            float yi1 = fmaf(a4, ks[4][1], fmaf(a3, ks[3][1], fmaf(a2, ks[2][1], fmaf(a1, ks[1][1], fmaf(a0, ks[0][1], y1)))));
            float yi2 = fmaf(a4, ks[4][2], fmaf(a3, ks[3][2], fmaf(a2, ks[2][2], fmaf(a1, ks[1][2], fmaf(a0, ks[0][2], y2)))));
            feval(t + dt_c, yi0, yi1, yi2, ks[5]); }
        const float db0 = dt_c*(float)(35.0/384.0), db2 = dt_c*(float)(500.0/1113.0),
                    db3 = dt_c*(float)(125.0/192.0), db4 = dt_c*(float)(-2187.0/6784.0),
                    db5 = dt_c*(float)(11.0/84.0);
        float y5_0 = fmaf(db5, ks[5][0], fmaf(db4, ks[4][0], fmaf(db3, ks[3][0], fmaf(db2, ks[2][0], fmaf(db0, ks[0][0], y0)))));
        float y5_1 = fmaf(db5, ks[5][1], fmaf(db4, ks[4][1], fmaf(db3, ks[3][1], fmaf(db2, ks[2][1], fmaf(db0, ks[0][1], y1)))));
        float y5_2 = fmaf(db5, ks[5][2], fmaf(db4, ks[4][2], fmaf(db3, ks[3][2], fmaf(db2, ks[2][2], fmaf(db0, ks[0][2], y2)))));
        // stage 7 input == y5 bit-exactly (A[6] == B), time t+dt_c  (FSAL)
        feval(t + dt_c, y5_0, y5_1, y5_2, ks[6]);

        const float de0 = dt_c*(float)(35.0/384.0   - 5179.0/57600.0);
        const float de2 = dt_c*(float)(500.0/1113.0 - 7571.0/16695.0);
        const float de3 = dt_c*(float)(125.0/192.0  - 393.0/640.0);
        const float de4 = dt_c*(float)(-2187.0/6784.0 + 92097.0/339200.0);
        const float de5 = dt_c*(float)(11.0/84.0    - 187.0/2100.0);
        const float de6 = dt_c*(float)(-1.0/40.0);
        float e_0 = fmaf(de6, ks[6][0], fmaf(de5, ks[5][0], fmaf(de4, ks[4][0], fmaf(de3, ks[3][0], fmaf(de2, ks[2][0], de0*ks[0][0])))));
        float e_1 = fmaf(de6, ks[6][1], fmaf(de5, ks[5][1], fmaf(de4, ks[4][1], fmaf(de3, ks[3][1], fmaf(de2, ks[2][1], de0*ks[0][1])))));
        float e_2 = fmaf(de6, ks[6][2], fmaf(de5, ks[5][2], fmaf(de4, ks[4][2], fmaf(de3, ks[3][2], fmaf(de2, ks[2][2], de0*ks[0][2])))));

        float e2 = 0.f;
        {   float tol = fmaf(1e-5f, fmaxf(fabsf(y0), fabsf(y5_0)), 1e-5f);
            float r = e_0 * __builtin_amdgcn_rcpf(tol); e2 = fmaf(r,r,e2); }
        {   float tol = fmaf(1e-5f, fmaxf(fabsf(y1), fabsf(y5_1)), 1e-5f);
            float r = e_1 * __builtin_amdgcn_rcpf(tol); e2 = fmaf(r,r,e2); }
        {   float tol = fmaf(1e-5f, fmaxf(fabsf(y2), fabsf(y5_2)), 1e-5f);
            float r = e_2 * __builtin_amdgcn_rcpf(tol); e2 = fmaf(r,r,e2); }

        float es = e2;
        es += __shfl_xor(es, 1); es += __shfl_xor(es, 2);
        es += __shfl_xor(es, 4); es += __shfl_xor(es, 8);
        if (lane == 0) cs8[w] = es;
        __syncthreads();

        unsigned long long* ph = slots + (s & 1)*NBLKS;
        if (w == 0) {
            if (lane == 0) {
                const float bs = ((cs8[0]+cs8[1]) + (cs8[2]+cs8[3]))
                               + ((cs8[4]+cs8[5]) + (cs8[6]+cs8[7]));
                const unsigned long long pack =
                    ((unsigned long long)(unsigned)(s + 1) << 32) |
                    (unsigned long long)__float_as_uint(bs);
                __hip_atomic_store(&ph[blockIdx.x], pack,
                                   __ATOMIC_RELAXED, __HIP_MEMORY_SCOPE_AGENT);
            }
            // only wave 0 polls; waves 1..7 sleep in the barrier below
            const unsigned long long m = (unsigned long long)(s + 1);
            unsigned long long u0, u1, u2, u3;
            for (;;) {
                u0 = ld_slot(&ph[lane      ]);
                u1 = ld_slot(&ph[lane +  64]);
                u2 = ld_slot(&ph[lane + 128]);
                u3 = ld_slot(&ph[lane + 192]);
                const bool ok = ((u0 >> 32) == m) & ((u1 >> 32) == m) &
                                ((u2 >> 32) == m) & ((u3 >> 32) == m);
                if (__ballot(ok) == ~0ull) break;
                __builtin_amdgcn_s_sleep(1);
            }
            float v = (__uint_as_float((uint32_t)u0) + __uint_as_float((uint32_t)u1))
                    + (__uint_as_float((uint32_t)u2) + __uint_as_float((uint32_t)u3));
            v += __shfl_xor(v, 1);  v += __shfl_xor(v, 2);  v += __shfl_xor(v, 4);
            v += __shfl_xor(v, 8);  v += __shfl_xor(v, 16); v += __shfl_xor(v, 32);
            if (lane == 0) vbox = v;
        }
        __syncthreads();
        const float v = vbox;

        float err = sqrtf(v / (float)N3);
        err = fmaxf(err, 1e-10f);
        const bool accept = (err <= 1.0f);
        const float factor = fminf(fmaxf(0.9f * __powf(err, -0.2f), 0.2f), 10.0f);
        if (accept) {
            t = t + dt_c; y0 = y5_0; y1 = y5_1; y2 = y5_2;
            ks[0][0] = ks[6][0]; ks[0][1] = ks[6][1]; ks[0][2] = ks[6][2];  // FSAL
        }
        dt = dt_c * factor;
        if ((1.0f - t) <= 1e-9f) break;     // uniform everywhere
    }

    if (q == 0) {
        out[3*gp+0] = y0; out[3*gp+1] = y1; out[3*gp+2] = y2;
    }
}

extern "C" void kernel_launch(void* const* d_in, const int* in_sizes, int n_in,
                              void* d_out, int out_size, void* d_ws, size_t ws_size,
                              hipStream_t stream) {
    const float* y  = (const float*)d_in[0];
    const float* W1 = (const float*)d_in[1];
    const float* b1 = (const float*)d_in[2];
    const float* W2 = (const float*)d_in[3];
    const float* b2 = (const float*)d_in[4];
    const float* W3 = (const float*)d_in[5];
    const float* b3 = (const float*)d_in[6];
    float* out = (float*)d_out;
    // 2 phases x 256 u64 slots; 0xAA poison top-32 never matches markers 1..24.
    unsigned long long* slots = (unsigned long long*)d_ws;

    ode_persist<<<dim3(NBLKS), dim3(TPB), 0, stream>>>(
        y, W1, b1, W2, b2, W3, b3, out, slots);
}